// Round 5
// baseline (127.965 us; speedup 1.0000x reference)
//
#include <hip/hip_runtime.h>
#include <hip/hip_bf16.h>
#include <math.h>

#define N_TOK 8192
#define D 512
#define NE 8

typedef float f32x4 __attribute__((ext_vector_type(4)));
typedef __bf16 bf16x8 __attribute__((ext_vector_type(8)));
typedef unsigned short u16;
typedef u16 u16x8 __attribute__((ext_vector_type(8)));

// ---- workspace layout (bytes) ----
// 0        int   count[8]
// 64       float imp[8]
// 256      int   tok_e[2*N_TOK]    (64 KB)
// 65792    float tok_g[2*N_TOK]    (64 KB)
// 131328   int   bucket[NE*N_TOK]  (256 KB)
// 1 MB     u16   xb[N_TOK*D]       (8 MB)   x in bf16
// 9 MB     u16   ewt[NE*D*D]       (4 MB)   expert_w [e][f][d] bf16
// 13 MB    u16   y[2*N_TOK*D]      (16 MB)  per-slot expert outputs bf16
#define OFF_TOKE  256
#define OFF_TOKG  65792
#define OFF_BUCK  131328
#define OFF_XB    (1u << 20)
#define OFF_EWT   (OFF_XB + 8u * 1024 * 1024)
#define OFF_Y     (OFF_EWT + 4u * 1024 * 1024)

__device__ __forceinline__ u16 f2b(float v) {
    __hip_bfloat16 h = __float2bfloat16(v);
    return *reinterpret_cast<u16*>(&h);
}
__device__ __forceinline__ float b2f(u16 u) {
    __hip_bfloat16 h;
    *reinterpret_cast<u16*>(&h) = u;
    return __bfloat162float(h);
}

typedef __attribute__((address_space(1))) const void* gp1_t;
typedef __attribute__((address_space(3))) void* lp3_t;
__device__ __forceinline__ void gload16(const void* g, void* l) {
    __builtin_amdgcn_global_load_lds((gp1_t)g, (lp3_t)l, 16, 0, 0);
}

// -------- fused: gate (blocks 0..2047) | prep_w transpose (blocks 2048..2559)
// NOTE: count/imp zero-init stays in hipMemsetAsync (round-3 post-mortem:
// kernel-store zeroing consumed by later-kernel atomics diverged on replay).
__global__ __launch_bounds__(256) void gate_prep_kernel(
    const float* __restrict__ x, const float* __restrict__ wg,
    const float* __restrict__ ew,
    int* __restrict__ tok_e, float* __restrict__ tok_g, u16* __restrict__ xb,
    u16* __restrict__ ewt)
{
    __shared__ __align__(16) float sbuf[64 * 65];   // 16.6 KB, both paths
    int b = blockIdx.x;
    int tid = threadIdx.x;

    if (b >= 2048) {
        // ---- prep path: expert_w [e][d][f] fp32 -> ewt [e][f][d] bf16
        int pb = b - 2048;
        float (*tile)[65] = (float(*)[65])sbuf;
        int e = pb >> 6, dt = (pb >> 3) & 7, ftl = pb & 7;
        int c = tid & 63, rq = tid >> 6;
        const float* src = ew + (size_t)e * D * D + (size_t)(dt * 64) * D + ftl * 64;
#pragma unroll
        for (int i = 0; i < 16; ++i) {
            int r = i * 4 + rq;
            tile[r][c] = src[(size_t)r * D + c];
        }
        __syncthreads();
        u16* dst = ewt + (size_t)e * D * D + (size_t)(ftl * 64) * D + dt * 64;
#pragma unroll
        for (int i = 0; i < 16; ++i) {
            int f = i * 4 + rq;
            dst[(size_t)f * D + c] = f2b(tile[c][f]);
        }
        return;
    }

    // ---- gate path (stride-64 wgs reads: 2-way bank alias only -> free)
    float* wgs = sbuf;   // [e][d] transposed
    for (int i = tid; i < NE * D; i += 256) {
        int d = i >> 3, e = i & 7;   // w_gate flat = d*8 + e
        wgs[e * D + d] = wg[i];
    }
    __syncthreads();

    int wave = tid >> 6, lane = tid & 63;
    int n = b * 4 + wave;
    const float* xr = x + (size_t)n * D;
    u16* xbr = xb + (size_t)n * D;

    float p[NE];
#pragma unroll
    for (int e = 0; e < NE; ++e) p[e] = 0.f;
#pragma unroll
    for (int it = 0; it < 8; ++it) {
        float xv = xr[it * 64 + lane];
        xbr[it * 64 + lane] = f2b(xv);
#pragma unroll
        for (int e = 0; e < NE; ++e)
            p[e] += xv * wgs[e * D + it * 64 + lane];
    }
#pragma unroll
    for (int off = 32; off > 0; off >>= 1) {
#pragma unroll
        for (int e = 0; e < NE; ++e)
            p[e] += __shfl_xor(p[e], off);
    }

    if (lane == 0) {
        // top-2, ties -> lowest index (jax.lax.top_k semantics)
        int e1 = 0; float v1 = p[0];
#pragma unroll
        for (int e = 1; e < NE; ++e) if (p[e] > v1) { v1 = p[e]; e1 = e; }
        int e2 = -1; float v2 = -INFINITY;
#pragma unroll
        for (int e = 0; e < NE; ++e) if (e != e1 && p[e] > v2) { v2 = p[e]; e2 = e; }
        float t = __expf(v2 - v1);
        float inv = 1.f / (1.f + t);
        tok_e[2 * n] = e1;     tok_e[2 * n + 1] = e2;
        tok_g[2 * n] = inv;    tok_g[2 * n + 1] = t * inv;
    }
}

// -------- bucketize: two-level offsets, 512 global atomics (round-2 proven)
__global__ __launch_bounds__(256) void bucketize_kernel(
    const int* __restrict__ tok_e, const float* __restrict__ tok_g,
    int* __restrict__ count, float* __restrict__ imp, int* __restrict__ bucket)
{
    __shared__ int lcnt[NE], lbase[NE];
    __shared__ float limp[NE];
    int tid = threadIdx.x;
    if (tid < NE) { lcnt[tid] = 0; limp[tid] = 0.f; }
    __syncthreads();

    int n = blockIdx.x * 256 + tid;
    int e1 = tok_e[2 * n], e2 = tok_e[2 * n + 1];
    float g1 = tok_g[2 * n], g2 = tok_g[2 * n + 1];
    int o1 = atomicAdd(&lcnt[e1], 1);
    int o2 = atomicAdd(&lcnt[e2], 1);
    atomicAdd(&limp[e1], g1);
    atomicAdd(&limp[e2], g2);
    __syncthreads();
    if (tid < NE) {
        lbase[tid] = atomicAdd(&count[tid], lcnt[tid]);
        atomicAdd(&imp[tid], limp[tid]);
    }
    __syncthreads();
    bucket[e1 * N_TOK + lbase[e1] + o1] = 2 * n;
    bucket[e2 * N_TOK + lbase[e2] + o2] = 2 * n + 1;
}

// -------- grouped GEMM, bf16 MFMA 16x16x32, 128x128 tile, BK=32,
// double-buffered LDS: ONE barrier per K-iter, gloads issued 1 iter ahead.
__global__ __launch_bounds__(256) void moe_gemm(
    const u16* __restrict__ xb, const u16* __restrict__ ewt,
    const int* __restrict__ count, const int* __restrict__ bucket,
    u16* __restrict__ y)
{
    int b = blockIdx.x;
    int ft = b & 3;            // feature tile (128 cols)
    int tt = (b >> 2) & 63;    // token tile (128 slots)
    int e  = b >> 8;           // expert
    int cnt = count[e];
    if (tt * 128 >= cnt) return;

    __shared__ int sl[128];
    // two buffers of (As 128x32 | Bs 128x32) u16 = 2 x 16384 elems = 64 KB.
    // epilogue reuses first 9216 elems of buf0.
    __shared__ __align__(16) u16 smem[32768];

    int tid = threadIdx.x;
    if (tid < 128) {
        int idx = tt * 128 + tid;
        sl[tid] = (idx < cnt) ? bucket[e * N_TOK + idx] : -1;
    }
    __syncthreads();

    int w = tid >> 6, l = tid & 63;
    int c8 = (l & 3) * 8;
    int r0 = w * 32 + (l >> 2);
    int r1 = r0 + 16;
    int s0 = sl[r0], s1 = sl[r1];
    int ta0 = (s0 < 0) ? 0 : (s0 >> 1);
    int ta1 = (s1 < 0) ? 0 : (s1 >> 1);
    const u16* gA0 = xb + (size_t)ta0 * D + c8;
    const u16* gA1 = xb + (size_t)ta1 * D + c8;
    const u16* gB0 = ewt + ((size_t)e * D + ft * 128 + r0) * D + c8;
    const u16* gB1 = ewt + ((size_t)e * D + ft * 128 + r1) * D + c8;
    // per-wave LDS staging bases (lane-contiguous: dest = base + lane*16B)
    int wo = w * 1024;   // (w*32)*32

    int wm = w & 1, wn = w >> 1;    // 2x2 waves, each 64x64 out
    int lm = l & 15, quad = l >> 4, kq = quad * 8;

    f32x4 acc[4][4] = {};

    // prologue: stage tile 0 into buf0
    {
        u16* nb = smem;
        gload16(gA0, nb + wo);
        gload16(gA1, nb + wo + 512);
        gload16(gB0, nb + 8192 + wo);
        gload16(gB1, nb + 8192 + wo + 512);
    }

    for (int kc = 0; kc < 16; ++kc) {
        // barrier: (a) drains gloads issued last iter -> buf[kc&1] valid;
        // (b) all waves done reading buf[(kc+1)&1] from iter kc-1.
        __syncthreads();
        if (kc < 15) {
            u16* nb = smem + ((kc + 1) & 1) * 16384;
            gload16(gA0 + (kc + 1) * 32, nb + wo);
            gload16(gA1 + (kc + 1) * 32, nb + wo + 512);
            gload16(gB0 + (kc + 1) * 32, nb + 8192 + wo);
            gload16(gB1 + (kc + 1) * 32, nb + 8192 + wo + 512);
        }
        const u16* As = smem + (kc & 1) * 16384;
        const u16* Bs = As + 8192;

        bf16x8 af[4], bfv[4];
#pragma unroll
        for (int i = 0; i < 4; ++i)
            af[i] = *(const bf16x8*)&As[(wm * 64 + i * 16 + lm) * 32 + kq];
#pragma unroll
        for (int j = 0; j < 4; ++j)
            bfv[j] = *(const bf16x8*)&Bs[(wn * 64 + j * 16 + lm) * 32 + kq];
#pragma unroll
        for (int i = 0; i < 4; ++i)
#pragma unroll
            for (int j = 0; j < 4; ++j)
                acc[i][j] = __builtin_amdgcn_mfma_f32_16x16x32_bf16(
                    af[i], bfv[j], acc[i][j], 0, 0, 0);
    }

    // ---- epilogue: per-wave LDS transpose, then coalesced 16B stores.
    // C/D layout (m89): col = lane&15, row = quad*4 + reg.
    __syncthreads();                 // all buf reads done before overwrite
    u16* Es = smem + w * 2304;       // 32 rows x 72 u16, 16B-aligned rows
#pragma unroll
    for (int h = 0; h < 2; ++h) {
#pragma unroll
        for (int i2 = 0; i2 < 2; ++i2) {
            int i = h * 2 + i2;
#pragma unroll
            for (int j = 0; j < 4; ++j)
#pragma unroll
                for (int r = 0; r < 4; ++r)
                    Es[(i2 * 16 + quad * 4 + r) * 72 + j * 16 + lm] =
                        f2b(acc[i][j][r]);
        }
        int row = l >> 1, hc = l & 1;        // 2 lanes per row, 64B halves
        int s = sl[wm * 64 + h * 32 + row];
        const u16* src = Es + row * 72 + hc * 32;
        u16* dst = y + (size_t)((s < 0) ? 0 : s) * D + ft * 128 + wn * 64 + hc * 32;
        if (s >= 0) {
#pragma unroll
            for (int c = 0; c < 4; ++c)
                *(u16x8*)(dst + c * 8) = *(const u16x8*)(src + c * 8);
        }
    }
}

// -------- combine (blocks 0..2047, 8 elem/thread) | loss (block 2048)
__global__ __launch_bounds__(256) void combine_kernel(
    const u16* __restrict__ y, const float* __restrict__ tok_g,
    const int* __restrict__ count, const float* __restrict__ imp,
    float* __restrict__ out)
{
    if (blockIdx.x == 2048) {
        if (threadIdx.x == 0) {
            float mi = 0.f, ml = 0.f;
            for (int e = 0; e < NE; ++e) { mi += imp[e]; ml += (float)count[e]; }
            mi *= 0.125f; ml *= 0.125f;
            float vi = 0.f, vl = 0.f;
            for (int e = 0; e < NE; ++e) {
                float di = imp[e] - mi;          vi += di * di;
                float dl = (float)count[e] - ml; vl += dl * dl;
            }
            vi *= 0.125f; vl *= 0.125f;
            out[N_TOK * D] = vi / (mi * mi + 1e-10f) + vl / (ml * ml + 1e-10f);
        }
        return;
    }
    int idx = blockIdx.x * 256 + threadIdx.x;   // 8-elem group id
    int n = idx >> 6;                           // 64 groups per token
    int c = (idx & 63) * 8;
    const u16x8 ua = *(const u16x8*)(y + (size_t)(2 * n) * D + c);
    const u16x8 ub = *(const u16x8*)(y + (size_t)(2 * n + 1) * D + c);
    float g1 = tok_g[2 * n], g2 = tok_g[2 * n + 1];
    const float eps = 2.2204460492503131e-16f;
    float r[8];
#pragma unroll
    for (int i = 0; i < 8; ++i) {
        float v = g1 * __expf(b2f(ua[i])) + g2 * __expf(b2f(ub[i]));
        r[i] = __logf(v == 0.f ? eps : v);
    }
    float* o = out + (size_t)n * D + c;
    *(float4*)(o)     = *(float4*)&r[0];
    *(float4*)(o + 4) = *(float4*)&r[4];
}

extern "C" void kernel_launch(void* const* d_in, const int* in_sizes, int n_in,
                              void* d_out, int out_size, void* d_ws, size_t ws_size,
                              hipStream_t stream)
{
    const float* x  = (const float*)d_in[0];
    const float* wg = (const float*)d_in[1];
    const float* ew = (const float*)d_in[2];
    char* ws = (char*)d_ws;
    int*   count  = (int*)(ws + 0);
    float* imp    = (float*)(ws + 64);
    int*   tok_e  = (int*)(ws + OFF_TOKE);
    float* tok_g  = (float*)(ws + OFF_TOKG);
    int*   bucket = (int*)(ws + OFF_BUCK);
    u16*   xb     = (u16*)(ws + OFF_XB);
    u16*   ewt    = (u16*)(ws + OFF_EWT);
    u16*   y      = (u16*)(ws + OFF_Y);
    float* out    = (float*)d_out;

    hipMemsetAsync(ws, 0, 128, stream);   // count + imp (replay-proven path)
    gate_prep_kernel<<<2048 + 512, 256, 0, stream>>>(x, wg, ew, tok_e, tok_g, xb, ewt);
    bucketize_kernel<<<N_TOK / 256, 256, 0, stream>>>(tok_e, tok_g, count, imp, bucket);
    moe_gemm<<<NE * 64 * 4, 256, 0, stream>>>(xb, ewt, count, bucket, y);
    combine_kernel<<<2049, 256, 0, stream>>>(y, tok_g, count, imp, out);
}

// Round 6
// 127.862 us; speedup vs baseline: 1.0008x; 1.0008x over previous
//
#include <hip/hip_runtime.h>
#include <hip/hip_bf16.h>
#include <math.h>

#define N_TOK 8192
#define D 512
#define NE 8

typedef float f32x4 __attribute__((ext_vector_type(4)));
typedef __bf16 bf16x8 __attribute__((ext_vector_type(8)));
typedef unsigned short u16;
typedef u16 u16x8 __attribute__((ext_vector_type(8)));

// ---- workspace layout (bytes) ----
// 0        int   count[8]
// 64       float imp[8]
// 256      int   tok_e[2*N_TOK]    (64 KB)
// 65792    float tok_g[2*N_TOK]    (64 KB)
// 131328   int   bucket[NE*N_TOK]  (256 KB)
// 1 MB     u16   xb[N_TOK*D]       (8 MB)   x in bf16
// 9 MB     u16   ewt[NE*D*D]       (4 MB)   expert_w [e][f][d] bf16
// 13 MB    u16   y[2*N_TOK*D]      (16 MB)  per-slot expert outputs bf16
#define OFF_TOKE  256
#define OFF_TOKG  65792
#define OFF_BUCK  131328
#define OFF_XB    (1u << 20)
#define OFF_EWT   (OFF_XB + 8u * 1024 * 1024)
#define OFF_Y     (OFF_EWT + 4u * 1024 * 1024)

__device__ __forceinline__ u16 f2b(float v) {
    __hip_bfloat16 h = __float2bfloat16(v);
    return *reinterpret_cast<u16*>(&h);
}
__device__ __forceinline__ float b2f(u16 u) {
    __hip_bfloat16 h;
    *reinterpret_cast<u16*>(&h) = u;
    return __bfloat162float(h);
}

typedef __attribute__((address_space(1))) const void* gp1_t;
typedef __attribute__((address_space(3))) void* lp3_t;
__device__ __forceinline__ void gload16(const void* g, void* l) {
    __builtin_amdgcn_global_load_lds((gp1_t)g, (lp3_t)l, 16, 0, 0);
}

// -------- fused: gate (blocks 0..2047) | prep_w transpose (blocks 2048..2559)
// NOTE: count/imp zero-init stays in hipMemsetAsync (round-3 post-mortem:
// kernel-store zeroing consumed by later-kernel atomics diverged on replay).
__global__ __launch_bounds__(256) void gate_prep_kernel(
    const float* __restrict__ x, const float* __restrict__ wg,
    const float* __restrict__ ew,
    int* __restrict__ tok_e, float* __restrict__ tok_g, u16* __restrict__ xb,
    u16* __restrict__ ewt)
{
    __shared__ __align__(16) float sbuf[64 * 65];   // 16.6 KB, both paths
    int b = blockIdx.x;
    int tid = threadIdx.x;

    if (b >= 2048) {
        // ---- prep path: expert_w [e][d][f] fp32 -> ewt [e][f][d] bf16
        int pb = b - 2048;
        float (*tile)[65] = (float(*)[65])sbuf;
        int e = pb >> 6, dt = (pb >> 3) & 7, ftl = pb & 7;
        int c = tid & 63, rq = tid >> 6;
        const float* src = ew + (size_t)e * D * D + (size_t)(dt * 64) * D + ftl * 64;
#pragma unroll
        for (int i = 0; i < 16; ++i) {
            int r = i * 4 + rq;
            tile[r][c] = src[(size_t)r * D + c];
        }
        __syncthreads();
        u16* dst = ewt + (size_t)e * D * D + (size_t)(ftl * 64) * D + dt * 64;
#pragma unroll
        for (int i = 0; i < 16; ++i) {
            int f = i * 4 + rq;
            dst[(size_t)f * D + c] = f2b(tile[c][f]);
        }
        return;
    }

    // ---- gate path
    float* wgs = sbuf;   // [e][d] transposed
    for (int i = tid; i < NE * D; i += 256) {
        int d = i >> 3, e = i & 7;   // w_gate flat = d*8 + e
        wgs[e * D + d] = wg[i];
    }
    __syncthreads();

    int wave = tid >> 6, lane = tid & 63;
    int n = b * 4 + wave;
    const float* xr = x + (size_t)n * D;
    u16* xbr = xb + (size_t)n * D;

    float p[NE];
#pragma unroll
    for (int e = 0; e < NE; ++e) p[e] = 0.f;
#pragma unroll
    for (int it = 0; it < 8; ++it) {
        float xv = xr[it * 64 + lane];
        xbr[it * 64 + lane] = f2b(xv);
#pragma unroll
        for (int e = 0; e < NE; ++e)
            p[e] += xv * wgs[e * D + it * 64 + lane];
    }
#pragma unroll
    for (int off = 32; off > 0; off >>= 1) {
#pragma unroll
        for (int e = 0; e < NE; ++e)
            p[e] += __shfl_xor(p[e], off);
    }

    if (lane == 0) {
        // top-2, ties -> lowest index (jax.lax.top_k semantics)
        int e1 = 0; float v1 = p[0];
#pragma unroll
        for (int e = 1; e < NE; ++e) if (p[e] > v1) { v1 = p[e]; e1 = e; }
        int e2 = -1; float v2 = -INFINITY;
#pragma unroll
        for (int e = 0; e < NE; ++e) if (e != e1 && p[e] > v2) { v2 = p[e]; e2 = e; }
        float t = __expf(v2 - v1);
        float inv = 1.f / (1.f + t);
        tok_e[2 * n] = e1;     tok_e[2 * n + 1] = e2;
        tok_g[2 * n] = inv;    tok_g[2 * n + 1] = t * inv;
    }
}

// -------- bucketize: two-level offsets, 512 global atomics (round-2 proven)
__global__ __launch_bounds__(256) void bucketize_kernel(
    const int* __restrict__ tok_e, const float* __restrict__ tok_g,
    int* __restrict__ count, float* __restrict__ imp, int* __restrict__ bucket)
{
    __shared__ int lcnt[NE], lbase[NE];
    __shared__ float limp[NE];
    int tid = threadIdx.x;
    if (tid < NE) { lcnt[tid] = 0; limp[tid] = 0.f; }
    __syncthreads();

    int n = blockIdx.x * 256 + tid;
    int e1 = tok_e[2 * n], e2 = tok_e[2 * n + 1];
    float g1 = tok_g[2 * n], g2 = tok_g[2 * n + 1];
    int o1 = atomicAdd(&lcnt[e1], 1);
    int o2 = atomicAdd(&lcnt[e2], 1);
    atomicAdd(&limp[e1], g1);
    atomicAdd(&limp[e2], g2);
    __syncthreads();
    if (tid < NE) {
        lbase[tid] = atomicAdd(&count[tid], lcnt[tid]);
        atomicAdd(&imp[tid], limp[tid]);
    }
    __syncthreads();
    bucket[e1 * N_TOK + lbase[e1] + o1] = 2 * n;
    bucket[e2 * N_TOK + lbase[e2] + o2] = 2 * n + 1;
}

// -------- grouped GEMM, bf16 MFMA 16x16x32, 64x128 tile, BK=32, single buffer.
// Round-6: tile shrunk 128x128 -> 64x128 for 4 live blocks/CU (was 2) —
// occupancy, not pipelining, hides the per-barrier vmcnt drain (m114/m99).
__global__ __launch_bounds__(256) void moe_gemm(
    const u16* __restrict__ xb, const u16* __restrict__ ewt,
    const int* __restrict__ count, const int* __restrict__ bucket,
    u16* __restrict__ y)
{
    int b = blockIdx.x;
    int ft = b & 3;            // feature tile (128 cols)
    int tt = (b >> 2) & 127;   // token tile (64 slots)
    int e  = b >> 9;           // expert
    int cnt = count[e];
    if (tt * 64 >= cnt) return;

    __shared__ int sl[64];
    // staging: A rows 0..63 x 32k = smem[0..2047], B feat 0..127 x 32k =
    // smem[2048..6143]. Epilogue overlays: 4 waves x (32 rows x 72) = 9216.
    __shared__ __align__(16) u16 smem[9216];

    int tid = threadIdx.x;
    if (tid < 64) {
        int idx = tt * 64 + tid;
        sl[tid] = (idx < cnt) ? bucket[e * N_TOK + idx] : -1;
    }
    __syncthreads();

    int w = tid >> 6, l = tid & 63;
    int c8 = (l & 3) * 8;
    // A staging: wave w -> rows 16w..16w+15 (1 gload16/lane)
    int ra = w * 16 + (l >> 2);
    int sa = sl[ra];
    const u16* gA = xb + (size_t)((sa < 0) ? 0 : (sa >> 1)) * D + c8;
    u16* lA = &smem[w * 512];           // lane-contiguous: +l*8 u16
    // B staging: wave w -> feature rows 32w..32w+31 (2 gload16/lane)
    int fb0 = w * 32 + (l >> 2);
    const u16* gB0 = ewt + ((size_t)e * D + ft * 128 + fb0) * D + c8;
    const u16* gB1 = gB0 + (size_t)16 * D;
    u16* lB0 = &smem[2048 + w * 1024];
    u16* lB1 = lB0 + 512;

    int wm = w & 1, wn = w >> 1;        // wave tile: 32 rows x 64 cols
    int lm = l & 15, quad = l >> 4, kq = quad * 8;

    f32x4 acc[2][4] = {};

    for (int kc = 0; kc < 16; ++kc) {
        __syncthreads();                // prev iter's LDS reads done
        gload16(gA + kc * 32, lA);
        gload16(gB0 + kc * 32, lB0);
        gload16(gB1 + kc * 32, lB1);
        __syncthreads();                // drains vmcnt -> LDS valid

        bf16x8 af[2], bfv[4];
#pragma unroll
        for (int i = 0; i < 2; ++i)
            af[i] = *(const bf16x8*)&smem[(wm * 32 + i * 16 + lm) * 32 + kq];
#pragma unroll
        for (int j = 0; j < 4; ++j)
            bfv[j] = *(const bf16x8*)&smem[2048 + (wn * 64 + j * 16 + lm) * 32 + kq];
#pragma unroll
        for (int i = 0; i < 2; ++i)
#pragma unroll
            for (int j = 0; j < 4; ++j)
                acc[i][j] = __builtin_amdgcn_mfma_f32_16x16x32_bf16(
                    af[i], bfv[j], acc[i][j], 0, 0, 0);
    }

    // ---- epilogue: per-wave LDS transpose, then coalesced 16B stores.
    // C/D layout (m89): col = lane&15, row = quad*4 + reg.
    __syncthreads();                    // all staging reads done before overwrite
    u16* Es = smem + w * 2304;          // 32 rows x 72 u16
#pragma unroll
    for (int i = 0; i < 2; ++i)
#pragma unroll
        for (int j = 0; j < 4; ++j)
#pragma unroll
            for (int r = 0; r < 4; ++r)
                Es[(i * 16 + quad * 4 + r) * 72 + j * 16 + lm] =
                    f2b(acc[i][j][r]);
    int row = l >> 1, hc = l & 1;       // 2 lanes per row, 64B halves
    int s = sl[wm * 32 + row];
    const u16* src = Es + row * 72 + hc * 32;
    u16* dst = y + (size_t)((s < 0) ? 0 : s) * D + ft * 128 + wn * 64 + hc * 32;
    if (s >= 0) {
#pragma unroll
        for (int c = 0; c < 4; ++c)
            *(u16x8*)(dst + c * 8) = *(const u16x8*)(src + c * 8);
    }
}

// -------- combine (blocks 0..2047, 8 elem/thread) | loss (block 2048)
__global__ __launch_bounds__(256) void combine_kernel(
    const u16* __restrict__ y, const float* __restrict__ tok_g,
    const int* __restrict__ count, const float* __restrict__ imp,
    float* __restrict__ out)
{
    if (blockIdx.x == 2048) {
        if (threadIdx.x == 0) {
            float mi = 0.f, ml = 0.f;
            for (int e = 0; e < NE; ++e) { mi += imp[e]; ml += (float)count[e]; }
            mi *= 0.125f; ml *= 0.125f;
            float vi = 0.f, vl = 0.f;
            for (int e = 0; e < NE; ++e) {
                float di = imp[e] - mi;          vi += di * di;
                float dl = (float)count[e] - ml; vl += dl * dl;
            }
            vi *= 0.125f; vl *= 0.125f;
            out[N_TOK * D] = vi / (mi * mi + 1e-10f) + vl / (ml * ml + 1e-10f);
        }
        return;
    }
    int idx = blockIdx.x * 256 + threadIdx.x;   // 8-elem group id
    int n = idx >> 6;                           // 64 groups per token
    int c = (idx & 63) * 8;
    const u16x8 ua = *(const u16x8*)(y + (size_t)(2 * n) * D + c);
    const u16x8 ub = *(const u16x8*)(y + (size_t)(2 * n + 1) * D + c);
    float g1 = tok_g[2 * n], g2 = tok_g[2 * n + 1];
    const float eps = 2.2204460492503131e-16f;
    float r[8];
#pragma unroll
    for (int i = 0; i < 8; ++i) {
        float v = g1 * __expf(b2f(ua[i])) + g2 * __expf(b2f(ub[i]));
        r[i] = __logf(v == 0.f ? eps : v);
    }
    float* o = out + (size_t)n * D + c;
    *(float4*)(o)     = *(float4*)&r[0];
    *(float4*)(o + 4) = *(float4*)&r[4];
}

extern "C" void kernel_launch(void* const* d_in, const int* in_sizes, int n_in,
                              void* d_out, int out_size, void* d_ws, size_t ws_size,
                              hipStream_t stream)
{
    const float* x  = (const float*)d_in[0];
    const float* wg = (const float*)d_in[1];
    const float* ew = (const float*)d_in[2];
    char* ws = (char*)d_ws;
    int*   count  = (int*)(ws + 0);
    float* imp    = (float*)(ws + 64);
    int*   tok_e  = (int*)(ws + OFF_TOKE);
    float* tok_g  = (float*)(ws + OFF_TOKG);
    int*   bucket = (int*)(ws + OFF_BUCK);
    u16*   xb     = (u16*)(ws + OFF_XB);
    u16*   ewt    = (u16*)(ws + OFF_EWT);
    u16*   y      = (u16*)(ws + OFF_Y);
    float* out    = (float*)d_out;

    hipMemsetAsync(ws, 0, 128, stream);   // count + imp (replay-proven path)
    gate_prep_kernel<<<2048 + 512, 256, 0, stream>>>(x, wg, ew, tok_e, tok_g, xb, ewt);
    bucketize_kernel<<<N_TOK / 256, 256, 0, stream>>>(tok_e, tok_g, count, imp, bucket);
    moe_gemm<<<NE * 128 * 4, 256, 0, stream>>>(xb, ewt, count, bucket, y);
    combine_kernel<<<2049, 256, 0, stream>>>(y, tok_g, count, imp, out);
}

// Round 7
// 123.971 us; speedup vs baseline: 1.0322x; 1.0314x over previous
//
#include <hip/hip_runtime.h>
#include <hip/hip_bf16.h>
#include <math.h>

#define N_TOK 8192
#define D 512
#define NE 8

typedef float f32x4 __attribute__((ext_vector_type(4)));
typedef __bf16 bf16x8 __attribute__((ext_vector_type(8)));
typedef unsigned short u16;
typedef u16 u16x8 __attribute__((ext_vector_type(8)));

// ---- workspace layout (bytes) ----
// 0        int   count[8]
// 64       float imp[8]
// 256      int   tok_e[2*N_TOK]    (64 KB)
// 65792    float tok_g[2*N_TOK]    (64 KB)
// 131328   int   bucket[NE*N_TOK]  (256 KB)
// 1 MB     u16   xb[N_TOK*D]       (8 MB)   x in bf16
// 9 MB     u16   ewt[NE*D*D]       (4 MB)   expert_w [e][f][d] bf16
// 13 MB    u16   y[2*N_TOK*D]      (16 MB)  per-slot expert outputs bf16
#define OFF_TOKE  256
#define OFF_TOKG  65792
#define OFF_BUCK  131328
#define OFF_XB    (1u << 20)
#define OFF_EWT   (OFF_XB + 8u * 1024 * 1024)
#define OFF_Y     (OFF_EWT + 4u * 1024 * 1024)

__device__ __forceinline__ u16 f2b(float v) {
    __hip_bfloat16 h = __float2bfloat16(v);
    return *reinterpret_cast<u16*>(&h);
}
__device__ __forceinline__ float b2f(u16 u) {
    __hip_bfloat16 h;
    *reinterpret_cast<u16*>(&h) = u;
    return __bfloat162float(h);
}

typedef __attribute__((address_space(1))) const void* gp1_t;
typedef __attribute__((address_space(3))) void* lp3_t;
__device__ __forceinline__ void gload16(const void* g, void* l) {
    __builtin_amdgcn_global_load_lds((gp1_t)g, (lp3_t)l, 16, 0, 0);
}

// -------- fused: gate (blocks 0..2047) | prep_w transpose (blocks 2048..2559)
// NOTE: count/imp zero-init stays in hipMemsetAsync (round-3 post-mortem:
// kernel-store zeroing consumed by later-kernel atomics diverged on replay).
__global__ __launch_bounds__(256) void gate_prep_kernel(
    const float* __restrict__ x, const float* __restrict__ wg,
    const float* __restrict__ ew,
    int* __restrict__ tok_e, float* __restrict__ tok_g, u16* __restrict__ xb,
    u16* __restrict__ ewt)
{
    __shared__ __align__(16) float sbuf[64 * 65];   // 16.6 KB, both paths
    int b = blockIdx.x;
    int tid = threadIdx.x;

    if (b >= 2048) {
        // ---- prep path: expert_w [e][d][f] fp32 -> ewt [e][f][d] bf16
        int pb = b - 2048;
        float (*tile)[65] = (float(*)[65])sbuf;
        int e = pb >> 6, dt = (pb >> 3) & 7, ftl = pb & 7;
        int c = tid & 63, rq = tid >> 6;
        const float* src = ew + (size_t)e * D * D + (size_t)(dt * 64) * D + ftl * 64;
#pragma unroll
        for (int i = 0; i < 16; ++i) {
            int r = i * 4 + rq;
            tile[r][c] = src[(size_t)r * D + c];
        }
        __syncthreads();
        u16* dst = ewt + (size_t)e * D * D + (size_t)(ftl * 64) * D + dt * 64;
#pragma unroll
        for (int i = 0; i < 16; ++i) {
            int f = i * 4 + rq;
            dst[(size_t)f * D + c] = f2b(tile[c][f]);
        }
        return;
    }

    // ---- gate path
    float* wgs = sbuf;   // [e][d] transposed
    for (int i = tid; i < NE * D; i += 256) {
        int d = i >> 3, e = i & 7;   // w_gate flat = d*8 + e
        wgs[e * D + d] = wg[i];
    }
    __syncthreads();

    int wave = tid >> 6, lane = tid & 63;
    int n = b * 4 + wave;
    const float* xr = x + (size_t)n * D;
    u16* xbr = xb + (size_t)n * D;

    float p[NE];
#pragma unroll
    for (int e = 0; e < NE; ++e) p[e] = 0.f;
#pragma unroll
    for (int it = 0; it < 8; ++it) {
        float xv = xr[it * 64 + lane];
        xbr[it * 64 + lane] = f2b(xv);
#pragma unroll
        for (int e = 0; e < NE; ++e)
            p[e] += xv * wgs[e * D + it * 64 + lane];
    }
#pragma unroll
    for (int off = 32; off > 0; off >>= 1) {
#pragma unroll
        for (int e = 0; e < NE; ++e)
            p[e] += __shfl_xor(p[e], off);
    }

    if (lane == 0) {
        // top-2, ties -> lowest index (jax.lax.top_k semantics)
        int e1 = 0; float v1 = p[0];
#pragma unroll
        for (int e = 1; e < NE; ++e) if (p[e] > v1) { v1 = p[e]; e1 = e; }
        int e2 = -1; float v2 = -INFINITY;
#pragma unroll
        for (int e = 0; e < NE; ++e) if (e != e1 && p[e] > v2) { v2 = p[e]; e2 = e; }
        float t = __expf(v2 - v1);
        float inv = 1.f / (1.f + t);
        tok_e[2 * n] = e1;     tok_e[2 * n + 1] = e2;
        tok_g[2 * n] = inv;    tok_g[2 * n + 1] = t * inv;
    }
}

// -------- bucketize: two-level offsets, 512 global atomics (round-2 proven)
__global__ __launch_bounds__(256) void bucketize_kernel(
    const int* __restrict__ tok_e, const float* __restrict__ tok_g,
    int* __restrict__ count, float* __restrict__ imp, int* __restrict__ bucket)
{
    __shared__ int lcnt[NE], lbase[NE];
    __shared__ float limp[NE];
    int tid = threadIdx.x;
    if (tid < NE) { lcnt[tid] = 0; limp[tid] = 0.f; }
    __syncthreads();

    int n = blockIdx.x * 256 + tid;
    int e1 = tok_e[2 * n], e2 = tok_e[2 * n + 1];
    float g1 = tok_g[2 * n], g2 = tok_g[2 * n + 1];
    int o1 = atomicAdd(&lcnt[e1], 1);
    int o2 = atomicAdd(&lcnt[e2], 1);
    atomicAdd(&limp[e1], g1);
    atomicAdd(&limp[e2], g2);
    __syncthreads();
    if (tid < NE) {
        lbase[tid] = atomicAdd(&count[tid], lcnt[tid]);
        atomicAdd(&imp[tid], limp[tid]);
    }
    __syncthreads();
    bucket[e1 * N_TOK + lbase[e1] + o1] = 2 * n;
    bucket[e2 * N_TOK + lbase[e2] + o2] = 2 * n + 1;
}

// -------- grouped GEMM, bf16 MFMA 16x16x32, 128x128 tile, BK=64 as TWO 32-k
// planes (keeps m97-proven stride-32 LDS layout + gload16 lane-contiguity),
// single buffer, 8 K-iters -> 16 barriers (was 32). Round-7 change.
__global__ __launch_bounds__(256) void moe_gemm(
    const u16* __restrict__ xb, const u16* __restrict__ ewt,
    const int* __restrict__ count, const int* __restrict__ bucket,
    u16* __restrict__ y)
{
    int b = blockIdx.x;
    int ft = b & 3;            // feature tile (128 cols)
    int tt = (b >> 2) & 63;    // token tile (128 slots)
    int e  = b >> 8;           // expert
    int cnt = count[e];
    if (tt * 128 >= cnt) return;

    __shared__ int sl[128];
    // A: planes 0/1 at [0,4096) u16 each (128 rows x 32 k, stride 32);
    // B: same at smem+8192. Total 32 KB. Epilogue overlays [0,9216).
    __shared__ __align__(16) u16 smem[16384];

    int tid = threadIdx.x;
    if (tid < 128) {
        int idx = tt * 128 + tid;
        sl[tid] = (idx < cnt) ? bucket[e * N_TOK + idx] : -1;
    }
    __syncthreads();

    int w = tid >> 6, l = tid & 63;
    int c8 = (l & 3) * 8;             // within-plane k offset (u16)
    int r0 = w * 32 + (l >> 2);       // staging rows r0, r0+16
    int r1 = r0 + 16;
    int s0 = sl[r0], s1 = sl[r1];
    const u16* gA0 = xb + (size_t)((s0 < 0) ? 0 : (s0 >> 1)) * D + c8;
    const u16* gA1 = xb + (size_t)((s1 < 0) ? 0 : (s1 >> 1)) * D + c8;
    const u16* gB0 = ewt + ((size_t)e * D + ft * 128 + r0) * D + c8;
    const u16* gB1 = ewt + ((size_t)e * D + ft * 128 + r1) * D + c8;
    // LDS staging dests (lane-contiguous: base + l*8 u16)
    u16* lA0 = &smem[w * 1024 + l * 8];          // plane0 rows r0-group
    u16* lA1 = &smem[w * 1024 + 512 + l * 8];    // plane0 rows r1-group
    u16* lB0 = &smem[8192 + w * 1024 + l * 8];
    u16* lB1 = &smem[8192 + w * 1024 + 512 + l * 8];

    int wm = w & 1, wn = w >> 1;      // 2x2 waves, each 64x64 out
    int lm = l & 15, quad = l >> 4, kq = quad * 8;

    f32x4 acc[4][4] = {};

    for (int kc = 0; kc < 8; ++kc) {
        const u16* pA0 = gA0 + kc * 64;
        const u16* pA1 = gA1 + kc * 64;
        const u16* pB0 = gB0 + kc * 64;
        const u16* pB1 = gB1 + kc * 64;
        __syncthreads();              // prev iter's LDS reads done
        gload16(pA0,      lA0);
        gload16(pA1,      lA1);
        gload16(pA0 + 32, lA0 + 4096);   // plane 1 (k 32..63)
        gload16(pA1 + 32, lA1 + 4096);
        gload16(pB0,      lB0);
        gload16(pB1,      lB1);
        gload16(pB0 + 32, lB0 + 4096);
        gload16(pB1 + 32, lB1 + 4096);
        __syncthreads();              // drains vmcnt -> LDS valid

#pragma unroll
        for (int ks = 0; ks < 2; ++ks) {
            const u16* As = smem + ks * 4096;
            const u16* Bs = smem + 8192 + ks * 4096;
            bf16x8 af[4], bfv[4];
#pragma unroll
            for (int i = 0; i < 4; ++i)
                af[i] = *(const bf16x8*)&As[(wm * 64 + i * 16 + lm) * 32 + kq];
#pragma unroll
            for (int j = 0; j < 4; ++j)
                bfv[j] = *(const bf16x8*)&Bs[(wn * 64 + j * 16 + lm) * 32 + kq];
#pragma unroll
            for (int i = 0; i < 4; ++i)
#pragma unroll
                for (int j = 0; j < 4; ++j)
                    acc[i][j] = __builtin_amdgcn_mfma_f32_16x16x32_bf16(
                        af[i], bfv[j], acc[i][j], 0, 0, 0);
        }
    }

    // ---- epilogue: per-wave LDS transpose, then coalesced 16B stores.
    // C/D layout (m89): col = lane&15, row = quad*4 + reg.
    __syncthreads();                 // all staging reads done before overwrite
    u16* Es = smem + w * 2304;       // 32 rows x 72 u16
#pragma unroll
    for (int h = 0; h < 2; ++h) {
#pragma unroll
        for (int i2 = 0; i2 < 2; ++i2) {
            int i = h * 2 + i2;
#pragma unroll
            for (int j = 0; j < 4; ++j)
#pragma unroll
                for (int r = 0; r < 4; ++r)
                    Es[(i2 * 16 + quad * 4 + r) * 72 + j * 16 + lm] =
                        f2b(acc[i][j][r]);
        }
        int row = l >> 1, hc = l & 1;        // 2 lanes per row, 64B halves
        int s = sl[wm * 64 + h * 32 + row];
        const u16* src = Es + row * 72 + hc * 32;
        u16* dst = y + (size_t)((s < 0) ? 0 : s) * D + ft * 128 + wn * 64 + hc * 32;
        if (s >= 0) {
#pragma unroll
            for (int c = 0; c < 4; ++c)
                *(u16x8*)(dst + c * 8) = *(const u16x8*)(src + c * 8);
        }
    }
}

// -------- combine (blocks 0..2047, 8 elem/thread) | loss (block 2048)
__global__ __launch_bounds__(256) void combine_kernel(
    const u16* __restrict__ y, const float* __restrict__ tok_g,
    const int* __restrict__ count, const float* __restrict__ imp,
    float* __restrict__ out)
{
    if (blockIdx.x == 2048) {
        if (threadIdx.x == 0) {
            float mi = 0.f, ml = 0.f;
            for (int e = 0; e < NE; ++e) { mi += imp[e]; ml += (float)count[e]; }
            mi *= 0.125f; ml *= 0.125f;
            float vi = 0.f, vl = 0.f;
            for (int e = 0; e < NE; ++e) {
                float di = imp[e] - mi;          vi += di * di;
                float dl = (float)count[e] - ml; vl += dl * dl;
            }
            vi *= 0.125f; vl *= 0.125f;
            out[N_TOK * D] = vi / (mi * mi + 1e-10f) + vl / (ml * ml + 1e-10f);
        }
        return;
    }
    int idx = blockIdx.x * 256 + threadIdx.x;   // 8-elem group id
    int n = idx >> 6;                           // 64 groups per token
    int c = (idx & 63) * 8;
    const u16x8 ua = *(const u16x8*)(y + (size_t)(2 * n) * D + c);
    const u16x8 ub = *(const u16x8*)(y + (size_t)(2 * n + 1) * D + c);
    float g1 = tok_g[2 * n], g2 = tok_g[2 * n + 1];
    const float eps = 2.2204460492503131e-16f;
    float r[8];
#pragma unroll
    for (int i = 0; i < 8; ++i) {
        float v = g1 * __expf(b2f(ua[i])) + g2 * __expf(b2f(ub[i]));
        r[i] = __logf(v == 0.f ? eps : v);
    }
    float* o = out + (size_t)n * D + c;
    *(float4*)(o)     = *(float4*)&r[0];
    *(float4*)(o + 4) = *(float4*)&r[4];
}

extern "C" void kernel_launch(void* const* d_in, const int* in_sizes, int n_in,
                              void* d_out, int out_size, void* d_ws, size_t ws_size,
                              hipStream_t stream)
{
    const float* x  = (const float*)d_in[0];
    const float* wg = (const float*)d_in[1];
    const float* ew = (const float*)d_in[2];
    char* ws = (char*)d_ws;
    int*   count  = (int*)(ws + 0);
    float* imp    = (float*)(ws + 64);
    int*   tok_e  = (int*)(ws + OFF_TOKE);
    float* tok_g  = (float*)(ws + OFF_TOKG);
    int*   bucket = (int*)(ws + OFF_BUCK);
    u16*   xb     = (u16*)(ws + OFF_XB);
    u16*   ewt    = (u16*)(ws + OFF_EWT);
    u16*   y      = (u16*)(ws + OFF_Y);
    float* out    = (float*)d_out;

    hipMemsetAsync(ws, 0, 128, stream);   // count + imp (replay-proven path)
    gate_prep_kernel<<<2048 + 512, 256, 0, stream>>>(x, wg, ew, tok_e, tok_g, xb, ewt);
    bucketize_kernel<<<N_TOK / 256, 256, 0, stream>>>(tok_e, tok_g, count, imp, bucket);
    moe_gemm<<<NE * 64 * 4, 256, 0, stream>>>(xb, ewt, count, bucket, y);
    combine_kernel<<<2049, 256, 0, stream>>>(y, tok_g, count, imp, out);
}